// Round 13
// baseline (101.981 us; speedup 1.0000x reference)
//
#include <hip/hip_runtime.h>
#include <stdint.h>

#define NC13 507
#define NC26 2028
#define NC52 8112
#define NCAND 10647
#define NCANDP 10648      // padded plane-major records (pad slot at 507)
#define PB13 0
#define PB26 508
#define PB52 2536
#define KSEL 512
#define POOLCAP 768
#define POOLTGT 640
#define SUPW 17           // padded SUP row stride (17 coprime 32 -> conflict-free)
#define CMW 17            // padded class-mask stride
#define HBINS 4096
#define NG4 2535          // float4 groups per image (507 s26 + 2028 s52)
#define NQ4 10140         // NG4*4
#define NTI 12168         // NQ4 + 507*4 (s13 quarters)

// ---------------------------------------------------------------------------
// Sort-key semantics (verified absmax 0.0 across rounds):
//   valid (xo>0):  bit63 | float_bits(xo)<<32 | (0x3FFF - n)   [digit>=0x800]
//   invalid     :  (0x3FFF - n)                                 [digit==0]
// Descending key order == (conf desc, index asc) of the reference exactly.
// Keys stored at plane-major slot i (coalesced); the VALUE carries n.
// ---------------------------------------------------------------------------
__device__ __forceinline__ unsigned long long make_key(float xo, int n) {
    const unsigned long long low = (unsigned long long)(0x3FFFu - (unsigned)n);
    return (xo > 0.0f)
        ? ((1ull << 63) | ((unsigned long long)__float_as_uint(xo) << 32) | low)
        : low;
}

// argmax key: monotone float map + (127-c) => u64 max == first-max argmax
__device__ __forceinline__ unsigned long long cls_key(float v, int c) {
    unsigned int u = __float_as_uint(v);
    u = (u & 0x80000000u) ? ~u : (u | 0x80000000u);
    return ((unsigned long long)u << 32) | (unsigned long long)(127 - c);
}

// ---------------------------------------------------------------------------
// Kernel 1: stream — reads the FULL input coalesced at high occupancy.
// Work item = (candidate-group, channel-quarter q). q-major layout keeps
// waves intra-channel. q0 also decodes geometry + emits sort key + histogram.
// Per-candidate argmax merged across quarters via global u64 atomicMax.
// grid (48, B), 256 threads. clsAll+hist pre-zeroed via one memset.
// ---------------------------------------------------------------------------
__global__ __launch_bounds__(256, 3) void stream_kernel(
    const float* __restrict__ in13,
    const float* __restrict__ in26,
    const float* __restrict__ in52,
    const float* __restrict__ a13,
    const float* __restrict__ a26,
    const float* __restrict__ a52,
    float* __restrict__ geo,
    unsigned long long* __restrict__ keys,
    unsigned long long* __restrict__ clsAll,
    unsigned int* __restrict__ hist)
{
    __shared__ unsigned int lh[HBINS];
    const int b = blockIdx.y;
    const int tid = threadIdx.x;
    for (int q = tid; q < HBINS; q += 256) lh[q] = 0;
    __syncthreads();

    const int ti = blockIdx.x * 256 + tid;
    unsigned long long* kb = keys + (size_t)b * NCANDP;
    unsigned long long* cbA = clsAll + (size_t)b * NCANDP;
    float* g = geo + (size_t)b * 5 * NCANDP;

    if (ti < NQ4) {
        // ---------------- float4 path (s26 / s52) ----------------
        const int q = ti / NG4;            // channel quarter 0..3
        const int group = ti - q * NG4;    // 0..2534
        const float* in; const float* anch; int HW, HW4, Hdim, pb, nb, a, g4; float ts;
        if (group < 507) {
            in = in26; anch = a26; HW = 676; HW4 = 169; Hdim = 26; ts = 16.f;
            pb = PB26; nb = NC13; a = group / 169; g4 = group - a * 169;
        } else {
            const int g2 = group - 507;
            in = in52; anch = a52; HW = 2704; HW4 = 676; Hdim = 52; ts = 8.f;
            pb = PB52; nb = NC13 + NC26; a = g2 / 676; g4 = g2 - a * 676;
        }
        const int hw = g4 * 4;
        const float4* p4 = reinterpret_cast<const float4*>(
            in + ((size_t)b * 255 + (size_t)a * 85) * HW) + g4;
        const int i0 = pb + a * HW + hw;

        if (q == 0) {
            const float4 txv = p4[0];
            const float4 tyv = p4[(size_t)HW4];
            const float4 twv = p4[(size_t)2 * HW4];
            const float4 thv = p4[(size_t)3 * HW4];
            const float4 xov = p4[(size_t)4 * HW4];
            // keys + valid-only LDS histogram
            const unsigned long long k0 = make_key(xov.x, nb + (hw + 0) * 3 + a);
            const unsigned long long k1 = make_key(xov.y, nb + (hw + 1) * 3 + a);
            const unsigned long long k2 = make_key(xov.z, nb + (hw + 2) * 3 + a);
            const unsigned long long k3 = make_key(xov.w, nb + (hw + 3) * 3 + a);
            kb[i0 + 0] = k0; kb[i0 + 1] = k1; kb[i0 + 2] = k2; kb[i0 + 3] = k3;
            if (xov.x > 0.f) atomicAdd(&lh[(unsigned)(k0 >> 52)], 1u);
            if (xov.y > 0.f) atomicAdd(&lh[(unsigned)(k1 >> 52)], 1u);
            if (xov.z > 0.f) atomicAdd(&lh[(unsigned)(k2 >> 52)], 1u);
            if (xov.w > 0.f) atomicAdd(&lh[(unsigned)(k3 >> 52)], 1u);
            // geometry decode (identical arithmetic to verified rounds)
            const float aw = anch[2 * a], ah = anch[2 * a + 1];
            float4 X1v, Y1v, X2v, Y2v, CFv;
#define DECC(comp, j) { \
            const int hwj = hw + j; \
            const int hj = hwj / Hdim, wj = hwj - hj * Hdim; \
            const float sx = 1.0f / (1.0f + expf(-txv.comp)); \
            const float sy = 1.0f / (1.0f + expf(-tyv.comp)); \
            const float cf = 1.0f / (1.0f + expf(-xov.comp)); \
            const float cx = ((float)wj + sx) * ts; \
            const float cy = ((float)hj + sy) * ts; \
            const float bw = aw * expf(twv.comp); \
            const float bh = ah * expf(thv.comp); \
            X1v.comp = cx - bw * 0.5f; Y1v.comp = cy - bh * 0.5f; \
            X2v.comp = cx + bw * 0.5f; Y2v.comp = cy + bh * 0.5f; \
            CFv.comp = cf; }
            DECC(x, 0) DECC(y, 1) DECC(z, 2) DECC(w, 3)
#undef DECC
            *reinterpret_cast<float4*>(g + (size_t)0 * NCANDP + i0) = X1v;
            *reinterpret_cast<float4*>(g + (size_t)1 * NCANDP + i0) = Y1v;
            *reinterpret_cast<float4*>(g + (size_t)2 * NCANDP + i0) = X2v;
            *reinterpret_cast<float4*>(g + (size_t)3 * NCANDP + i0) = Y2v;
            *reinterpret_cast<float4*>(g + (size_t)4 * NCANDP + i0) = CFv;
        }

        // 20 class channels [q*20, q*20+20), batched 4-deep
        const int cbase = q * 20;
        const float4* pc = p4 + (size_t)(5 + cbase) * HW4;
        unsigned long long m0 = 0, m1 = 0, m2 = 0, m3 = 0;
        float4 vb[4];
        #pragma unroll
        for (int j = 0; j < 4; ++j) vb[j] = pc[(size_t)j * HW4];
        for (int t = 0; t < 5; ++t) {
            float4 vn[4];
            if (t < 4) {
                #pragma unroll
                for (int j = 0; j < 4; ++j) vn[j] = pc[(size_t)(t * 4 + 4 + j) * HW4];
            }
            #pragma unroll
            for (int j = 0; j < 4; ++j) {
                const int c = cbase + t * 4 + j;
                unsigned long long k;
                k = cls_key(vb[j].x, c); if (k > m0) m0 = k;
                k = cls_key(vb[j].y, c); if (k > m1) m1 = k;
                k = cls_key(vb[j].z, c); if (k > m2) m2 = k;
                k = cls_key(vb[j].w, c); if (k > m3) m3 = k;
            }
            #pragma unroll
            for (int j = 0; j < 4; ++j) vb[j] = vn[j];
        }
        atomicMax(&cbA[i0 + 0], m0);
        atomicMax(&cbA[i0 + 1], m1);
        atomicMax(&cbA[i0 + 2], m2);
        atomicMax(&cbA[i0 + 3], m3);
    } else if (ti < NTI) {
        // ---------------- scalar path (s13) ----------------
        const int t = ti - NQ4;
        const int q = t / 507;
        const int cand = t - q * 507;
        const int a = cand / 169, hw = cand - a * 169;
        const float* p = in13 + ((size_t)b * 255 + (size_t)a * 85) * 169 + hw;
        const int i = a * 169 + hw;        // PB13 == 0

        if (q == 0) {
            const float tx = p[0];
            const float ty = p[169];
            const float tw = p[2 * 169];
            const float th = p[3 * 169];
            const float xo = p[4 * 169];
            const int n = hw * 3 + a;
            const unsigned long long k = make_key(xo, n);
            kb[i] = k;
            if (xo > 0.f) atomicAdd(&lh[(unsigned)(k >> 52)], 1u);
            const int h = hw / 13, w = hw - h * 13;
            const float sx = 1.0f / (1.0f + expf(-tx));
            const float sy = 1.0f / (1.0f + expf(-ty));
            const float cf = 1.0f / (1.0f + expf(-xo));
            const float cx = ((float)w + sx) * 32.f;
            const float cy = ((float)h + sy) * 32.f;
            const float bw = a13[2 * a] * expf(tw);
            const float bh = a13[2 * a + 1] * expf(th);
            g[(size_t)0 * NCANDP + i] = cx - bw * 0.5f;
            g[(size_t)1 * NCANDP + i] = cy - bh * 0.5f;
            g[(size_t)2 * NCANDP + i] = cx + bw * 0.5f;
            g[(size_t)3 * NCANDP + i] = cy + bh * 0.5f;
            g[(size_t)4 * NCANDP + i] = cf;
        }

        const int cbase = q * 20;
        const float* pc = p + (size_t)(5 + cbase) * 169;
        unsigned long long m = 0;
        float vb[4];
        #pragma unroll
        for (int j = 0; j < 4; ++j) vb[j] = pc[(size_t)j * 169];
        for (int t2 = 0; t2 < 5; ++t2) {
            float vn[4];
            if (t2 < 4) {
                #pragma unroll
                for (int j = 0; j < 4; ++j) vn[j] = pc[(size_t)(t2 * 4 + 4 + j) * 169];
            }
            #pragma unroll
            for (int j = 0; j < 4; ++j) {
                const int c = cbase + t2 * 4 + j;
                const unsigned long long k = cls_key(vb[j], c);
                if (k > m) m = k;
            }
            #pragma unroll
            for (int j = 0; j < 4; ++j) vb[j] = vn[j];
        }
        atomicMax(&cbA[i], m);
    } else if (ti == NTI) {
        kb[507] = 0ull;                    // pad slot: below every real key
    }

    __syncthreads();
    unsigned int* hb = hist + (size_t)b * HBINS;
    for (int q = tid; q < HBINS; q += 256) {
        const unsigned int v = lh[q];
        if (v) atomicAdd(&hb[q], v);
    }
}

// ---------------------------------------------------------------------------
// Kernel 2: selnms — exact top-512 from precomputed histogram + NMS, fused.
// One block per image, 1024 threads (verified R12 select + R10 NMS bodies).
// ---------------------------------------------------------------------------
struct SelS {
    unsigned int hist[HBINS];
    unsigned long long pool[POOLCAP];
};
struct NmsS {
    float X1[KSEL], Y1[KSEL], X2[KSEL], Y2[KSEL], AR[KSEL], CF[KSEL];
    int CLS[KSEL];
    unsigned int CM[80 * CMW];
    unsigned int SUP[KSEL * SUPW];
    unsigned int KEEP[16];
};

__global__ __launch_bounds__(1024) void selnms_kernel(
    const unsigned long long* __restrict__ keys,
    const unsigned int* __restrict__ hist,
    const float* __restrict__ geo,
    const unsigned long long* __restrict__ clsAll,
    float* __restrict__ out)
{
    constexpr size_t USZ = sizeof(SelS) > sizeof(NmsS) ? sizeof(SelS) : sizeof(NmsS);
    __shared__ __align__(16) char smem[USZ];
    __shared__ int selidxL[KSEL];
    __shared__ unsigned long long sh_prefix, sh_tmin;
    __shared__ int sh_krem, sh_shift, sh_brk, sh_V;
    __shared__ unsigned int sh_cnt;

    const int b = blockIdx.x;
    const int tid = threadIdx.x;
    const unsigned long long* kb = keys + (size_t)b * NCANDP;
    SelS& S = *reinterpret_cast<SelS*>(smem);

    {
        const unsigned int* gh = hist + (size_t)b * HBINS;
        for (int i = tid; i < HBINS; i += 1024) S.hist[i] = gh[i];
    }
    if (tid == 0) { sh_cnt = 0; sh_prefix = 0; sh_krem = KSEL; sh_shift = 52; sh_brk = 0; }
    __syncthreads();

    // V = total valid (valid-only histogram); patch bin 0 in degenerate case
    if (tid < 64) {
        unsigned int s = 0;
        for (int q = 0; q < 64; ++q) s += S.hist[tid * 64 + q];
        #pragma unroll
        for (int off = 32; off; off >>= 1) s += __shfl_xor(s, off);
        if (tid == 0) sh_V = (int)s;
    }
    __syncthreads();
    if (tid == 0 && sh_V < KSEL) S.hist[0] += (unsigned)(NCAND - sh_V);
    __syncthreads();

    while (true) {
        const int shift = sh_shift;
        const unsigned long long prefix = sh_prefix;
        const int krem = sh_krem;
        if (tid < 64) {
            unsigned int s = 0;
            for (int q = 0; q < 64; ++q) s += S.hist[tid * 64 + q];
            unsigned int suf = s;
            for (int off = 1; off < 64; off <<= 1) {
                const unsigned int v = __shfl_down(suf, off);
                if (tid + off < 64) suf += v;
            }
            const unsigned long long ball = __ballot(suf >= (unsigned)krem);
            const int lstar = 63 - __clzll(ball);
            const unsigned int base = (lstar < 63) ? __shfl(suf, lstar + 1) : 0u;
            const unsigned int wv = S.hist[lstar * 64 + (63 - tid)];
            unsigned int pv = wv;
            for (int off = 1; off < 64; off <<= 1) {
                const unsigned int v = __shfl_up(pv, off);
                if (tid >= (unsigned)off) pv += v;
            }
            const unsigned long long b2 = __ballot(base + pv >= (unsigned)krem);
            const int mstar = __ffsll(b2) - 1;
            const unsigned int pvm = __shfl(pv, mstar);
            const unsigned int wvm = __shfl(wv, mstar);
            if (tid == 0) {
                const int dstar = lstar * 64 + (63 - mstar);
                const unsigned long long np = (prefix << 12) | (unsigned long long)dstar;
                const int Albl = (int)(base + pvm - wvm);
                const int Cpool = (KSEL - krem) + Albl + (int)wvm;
                sh_prefix = np;
                sh_krem = krem - Albl;
                if (Cpool <= POOLTGT || shift == 4) {
                    sh_brk = 1;
                    sh_tmin = np << shift;
                } else {
                    sh_shift = shift - 12;
                }
            }
        }
        __syncthreads();
        if (sh_brk) break;

        // rare exact-refinement: rebuild histogram at finer shift from keys
        const int nshift = sh_shift;
        const unsigned long long nprefix = sh_prefix;
        for (int i = tid; i < HBINS; i += 1024) S.hist[i] = 0;
        __syncthreads();
        for (int i = tid; i < NCANDP; i += 1024) {
            const unsigned long long k = kb[i];
            if ((k >> (nshift + 12)) == nprefix)
                atomicAdd(&S.hist[(unsigned)((k >> nshift) & 0xFFFull)], 1u);
        }
        __syncthreads();
    }
    const unsigned long long tmin = sh_tmin;

    for (int i = tid; i < NCANDP; i += 1024) {
        const unsigned long long k = kb[i];
        if (k >= tmin) {
            const unsigned int p = atomicAdd(&sh_cnt, 1u);
            if (p < POOLCAP) S.pool[p] = k;
        }
    }
    __syncthreads();
    const int C = ((int)sh_cnt < POOLCAP) ? (int)sh_cnt : POOLCAP;

    for (int p = tid; p < C; p += 1024) {
        const unsigned long long k = S.pool[p];
        int r = 0;
        for (int j = 0; j < C; ++j) r += (S.pool[j] > k) ? 1 : 0;
        if (r < KSEL) {
            int idx = 0x3FFF - (int)(k & 0x3FFFull);
            if (idx > NCAND - 1) idx = NCAND - 1;   // impossible-degenerate guard
            selidxL[r] = idx;
        }
    }
    const int V = (sh_V < KSEL) ? sh_V : KSEL;   // valid is a prefix of ranks
    __syncthreads();

    // ======================= NMS phase =======================
    NmsS& M = *reinterpret_cast<NmsS*>(smem);
    const int t5 = tid & 511;
    const int half = tid >> 9;

    const int n = selidxL[t5];
    int pb, HW, nb;
    if (n < NC13)             { pb = PB13; HW = 169;  nb = 0; }
    else if (n < NC13 + NC26) { pb = PB26; HW = 676;  nb = NC13; }
    else                      { pb = PB52; HW = 2704; nb = NC13 + NC26; }
    const int loc = n - nb;
    const int hw = loc / 3, a = loc - 3 * hw;
    const int i = pb + a * HW + hw;

    if (half == 0) {
        const float* g = geo + (size_t)b * 5 * NCANDP;
        const float x1 = g[(size_t)0 * NCANDP + i];
        const float y1 = g[(size_t)1 * NCANDP + i];
        const float x2 = g[(size_t)2 * NCANDP + i];
        const float y2 = g[(size_t)3 * NCANDP + i];
        M.X1[t5] = x1; M.Y1[t5] = y1; M.X2[t5] = x2; M.Y2[t5] = y2;
        M.AR[t5] = (x2 - x1) * (y2 - y1);
        M.CF[t5] = g[(size_t)4 * NCANDP + i];
        M.CLS[t5] = 127 - (int)(clsAll[(size_t)b * NCANDP + i] & 0x7Full);
    }
    for (int q = tid; q < 80 * CMW; q += 1024) M.CM[q] = 0;
    __syncthreads();

    const float x1 = M.X1[t5], y1 = M.Y1[t5], x2 = M.X2[t5], y2 = M.Y2[t5];
    const float ar = M.AR[t5];
    const int ci = M.CLS[t5];
    if (half == 0) atomicOr(&M.CM[ci * CMW + (t5 >> 5)], 1u << (t5 & 31));
    __syncthreads();

    for (int wj = half * 8; wj < half * 8 + 8; ++wj) {
        unsigned int m = M.CM[ci * CMW + wj];
        unsigned int bits = 0;
        while (m) {
            const int bit = __ffs(m) - 1;
            m &= m - 1;
            const int j = wj * 32 + bit;
            const float iw = fminf(x2, M.X2[j]) - fmaxf(x1, M.X1[j]);
            const float ih = fminf(y2, M.Y2[j]) - fmaxf(y1, M.Y1[j]);
            if (iw > 0.0f && ih > 0.0f) {
                const float inter = iw * ih;
                if (inter > 0.3f * (ar + M.AR[j] - inter + 1e-9f))
                    bits |= (1u << bit);
            }
        }
        M.SUP[t5 * SUPW + wj] = bits;
    }
    __syncthreads();

    // sequential greedy scan (exact lax.scan semantics), wave 0 only
    if (tid < 64) {
        unsigned int keepw = 0;       // lanes 0..15 hold the 512-bit keep mask
        unsigned int buf[16];
        #pragma unroll
        for (int q = 0; q < 16; ++q)
            buf[q] = (tid < 16) ? M.SUP[q * SUPW + tid] : 0u;
        for (int gg = 0; gg < 32; ++gg) {
            unsigned int nbuf[16] = {0};
            if (gg < 31) {
                #pragma unroll
                for (int q = 0; q < 16; ++q)
                    nbuf[q] = (tid < 16) ? M.SUP[((gg + 1) * 16 + q) * SUPW + tid] : 0u;
            }
            #pragma unroll
            for (int q = 0; q < 16; ++q) {
                const int ii = gg * 16 + q;
                const bool anysup = __any((keepw & buf[q]) != 0u);
                const bool ki = (ii < V) && !anysup;
                if (ki && tid == (ii >> 5)) keepw |= (1u << (ii & 31));
            }
            #pragma unroll
            for (int q = 0; q < 16; ++q) buf[q] = nbuf[q];
        }
        if (tid < 16) M.KEEP[tid] = keepw;
    }
    __syncthreads();

    if (tid < 512) {
        const float kf = ((M.KEEP[t5 >> 5] >> (t5 & 31)) & 1u) ? 1.0f : 0.0f;
        float* dst = out + ((size_t)b * KSEL + t5) * 7;
        dst[0] = x1; dst[1] = y1; dst[2] = x2; dst[3] = y2;
        dst[4] = M.CF[t5]; dst[5] = (float)ci; dst[6] = kf;
    }
}

// ---------------------------------------------------------------------------
extern "C" void kernel_launch(void* const* d_in, const int* in_sizes, int n_in,
                              void* d_out, int out_size, void* d_ws, size_t ws_size,
                              hipStream_t stream)
{
    (void)n_in; (void)out_size; (void)ws_size;
    const float* in13 = (const float*)d_in[0];
    const float* in26 = (const float*)d_in[1];
    const float* in52 = (const float*)d_in[2];
    const float* a13  = (const float*)d_in[3];
    const float* a26  = (const float*)d_in[4];
    const float* a52  = (const float*)d_in[5];
    float* out = (float*)d_out;
    const int B = in_sizes[0] / (255 * 169);

    char* w = (char*)d_ws;
    unsigned long long* keys = (unsigned long long*)w;
    w += ((size_t)B * NCANDP * sizeof(unsigned long long) + 255) & ~(size_t)255;
    float* geo = (float*)w;
    w += ((size_t)B * 5 * NCANDP * sizeof(float) + 255) & ~(size_t)255;
    // clsAll and hist adjacent -> single memset zeroes both
    unsigned long long* clsAll = (unsigned long long*)w;
    const size_t clsBytes = (((size_t)B * NCANDP * sizeof(unsigned long long)) + 255) & ~(size_t)255;
    w += clsBytes;
    unsigned int* hist = (unsigned int*)w;
    const size_t histBytes = (((size_t)B * HBINS * sizeof(unsigned int)) + 255) & ~(size_t)255;
    w += histBytes;

    hipMemsetAsync(clsAll, 0, clsBytes + histBytes, stream);
    stream_kernel<<<dim3(48, B), 256, 0, stream>>>(
        in13, in26, in52, a13, a26, a52, geo, keys, clsAll, hist);
    selnms_kernel<<<dim3(B), 1024, 0, stream>>>(keys, hist, geo, clsAll, out);
}

// Round 14
// 69.703 us; speedup vs baseline: 1.4631x; 1.4631x over previous
//
#include <hip/hip_runtime.h>
#include <stdint.h>

#define NC13 507
#define NC26 2028
#define NC52 8112
#define NCAND 10647
#define NCANDP 10648      // padded plane-major records
#define PB13 0
#define PB26 508
#define PB52 2536
#define KSEL 512
#define POOLCAP 768
#define POOLTGT 640
#define SUPW 17           // padded SUP row stride (17 coprime 32 -> conflict-free)
#define CMW 17            // padded class-mask stride
#define HBINS 4096

// ---------------------------------------------------------------------------
// Sort-key semantics (verified absmax 0.0 across rounds):
//   valid (xo>0):  bit63 | float_bits(xo)<<32 | (0x3FFF - n)   [digit>=0x800]
//   invalid     :  (0x3FFF - n)                                 [digit==0]
// Descending key order == (conf desc, index asc) of the reference exactly.
// ---------------------------------------------------------------------------
__device__ __forceinline__ unsigned long long make_key(float xo, int n) {
    const unsigned long long low = (unsigned long long)(0x3FFFu - (unsigned)n);
    return (xo > 0.0f)
        ? ((1ull << 63) | ((unsigned long long)__float_as_uint(xo) << 32) | low)
        : low;
}

// candidate key recomputed from input (select path; plane-major i)
__device__ __forceinline__ unsigned long long cand_key(
    int i, int b,
    const float* __restrict__ in13,
    const float* __restrict__ in26,
    const float* __restrict__ in52)
{
    const float* in; int HW, base;
    if (i < NC13)              { in = in13; HW = 169;  base = 0; }
    else if (i < NC13 + NC26)  { in = in26; HW = 676;  base = NC13; }
    else                       { in = in52; HW = 2704; base = NC13 + NC26; }
    const int within = i - base;
    const int a  = within / HW;
    const int hw = within - a * HW;
    const float xo = in[((size_t)b * 255 + (size_t)a * 85 + 4) * HW + hw];
    return make_key(xo, base + hw * 3 + a);
}

// argmax key: monotone float map + (127-c) => u64 max == first-max argmax
__device__ __forceinline__ unsigned long long cls_key(float v, int c) {
    unsigned int u = __float_as_uint(v);
    u = (u & 0x80000000u) ? ~u : (u | 0x80000000u);
    return ((unsigned long long)u << 32) | (unsigned long long)(127 - c);
}

struct SelS {
    unsigned int hist[HBINS];
    unsigned long long pool[POOLCAP];
};

// ---------------------------------------------------------------------------
// MEGA kernel: grid = B*7 blocks, 1024 threads.
//   role 0: per-image exact top-512 select (reads ch4 only, recomputes keys)
//   roles 1-4: s52 decode (512 quads each); role 5: s26 (507 quads);
//   role 6: s13 (507 scalars). Decode = thread-PAIR per quad:
//   half A: ch0-4 geo + classes 0-39; half B: classes 40-79; LDS u64 merge.
// ---------------------------------------------------------------------------
__global__ __launch_bounds__(1024, 4) void mega_kernel(
    const float* __restrict__ in13,
    const float* __restrict__ in26,
    const float* __restrict__ in52,
    const float* __restrict__ a13,
    const float* __restrict__ a26,
    const float* __restrict__ a52,
    float* __restrict__ geo,          // 6 planes x NCANDP per image
    int* __restrict__ selidx,
    int* __restrict__ selV)
{
    constexpr size_t USZ = sizeof(SelS) > (2048 * 8) ? sizeof(SelS) : (2048 * 8);
    __shared__ __align__(16) char smem[USZ];
    const int bid = blockIdx.x;
    const int role = bid % 7;
    const int b = bid / 7;
    const int tid = threadIdx.x;

    if (role == 0) {
        // ========================= SELECT =========================
        SelS& S = *reinterpret_cast<SelS*>(smem);
        __shared__ unsigned long long sh_prefix, sh_tmin;
        __shared__ int sh_krem, sh_shift, sh_brk, sh_V;
        __shared__ unsigned int sh_cnt;

        for (int i = tid; i < HBINS; i += 1024) S.hist[i] = 0;
        if (tid == 0) { sh_cnt = 0; sh_prefix = 0; sh_krem = KSEL; sh_shift = 52; sh_brk = 0; sh_V = 0; }
        __syncthreads();

        // pass 1: valid-only histogram at shift 52 + V count (merged)
        {
            int vAcc = 0;
            for (int i = tid; i < NCAND; i += 1024) {
                const unsigned long long k = cand_key(i, b, in13, in26, in52);
                const bool valid = (k >> 63) != 0ull;
                if (valid) atomicAdd(&S.hist[(unsigned)(k >> 52)], 1u);
                const unsigned long long bal = __ballot(valid);
                if ((tid & 63) == 0) vAcc += __popcll(bal);
            }
            if ((tid & 63) == 0 && vAcc) atomicAdd(&sh_V, vAcc);
        }
        __syncthreads();
        const int V = sh_V;
        const bool include = (V < KSEL);          // degenerate fallback only
        if (tid == 0 && include) S.hist[0] += (unsigned)(NCAND - V);
        __syncthreads();

        while (true) {
            const int shift = sh_shift;
            const unsigned long long prefix = sh_prefix;
            const int krem = sh_krem;
            if (tid < 64) {
                unsigned int s = 0;
                for (int q = 0; q < 64; ++q) s += S.hist[tid * 64 + q];
                unsigned int suf = s;
                for (int off = 1; off < 64; off <<= 1) {
                    const unsigned int v = __shfl_down(suf, off);
                    if (tid + off < 64) suf += v;
                }
                const unsigned long long ball = __ballot(suf >= (unsigned)krem);
                const int lstar = 63 - __clzll(ball);
                const unsigned int base = (lstar < 63) ? __shfl(suf, lstar + 1) : 0u;
                const unsigned int wv = S.hist[lstar * 64 + (63 - tid)];
                unsigned int pv = wv;
                for (int off = 1; off < 64; off <<= 1) {
                    const unsigned int v = __shfl_up(pv, off);
                    if (tid >= (unsigned)off) pv += v;
                }
                const unsigned long long b2 = __ballot(base + pv >= (unsigned)krem);
                const int mstar = __ffsll(b2) - 1;
                const unsigned int pvm = __shfl(pv, mstar);
                const unsigned int wvm = __shfl(wv, mstar);
                if (tid == 0) {
                    const int dstar = lstar * 64 + (63 - mstar);
                    const unsigned long long np = (prefix << 12) | (unsigned long long)dstar;
                    const int Albl = (int)(base + pvm - wvm);
                    const int Cpool = (KSEL - krem) + Albl + (int)wvm;
                    sh_prefix = np;
                    sh_krem = krem - Albl;
                    if (Cpool <= POOLTGT || shift == 4) {
                        sh_brk = 1;
                        sh_tmin = np << shift;
                    } else {
                        sh_shift = shift - 12;
                    }
                }
            }
            __syncthreads();
            if (sh_brk) break;

            // rare exact-refinement: rebuild histogram at finer shift
            const int nshift = sh_shift;
            const unsigned long long nprefix = sh_prefix;
            for (int i = tid; i < HBINS; i += 1024) S.hist[i] = 0;
            __syncthreads();
            for (int i = tid; i < NCAND; i += 1024) {
                const unsigned long long k = cand_key(i, b, in13, in26, in52);
                const bool part = include || ((k >> 63) != 0ull);
                if (part && ((k >> (nshift + 12)) == nprefix))
                    atomicAdd(&S.hist[(unsigned)((k >> nshift) & 0xFFFull)], 1u);
            }
            __syncthreads();
        }
        const unsigned long long tmin = sh_tmin;

        for (int i = tid; i < NCAND; i += 1024) {
            const unsigned long long k = cand_key(i, b, in13, in26, in52);
            if (k >= tmin) {
                const unsigned int p = atomicAdd(&sh_cnt, 1u);
                if (p < POOLCAP) S.pool[p] = k;
            }
        }
        __syncthreads();
        const int C = ((int)sh_cnt < POOLCAP) ? (int)sh_cnt : POOLCAP;

        for (int p = tid; p < C; p += 1024) {
            const unsigned long long k = S.pool[p];
            int r = 0;
            for (int j = 0; j < C; ++j) r += (S.pool[j] > k) ? 1 : 0;
            if (r < KSEL) {
                int idx = 0x3FFF - (int)(k & 0x3FFFull);
                if (idx > NCAND - 1) idx = NCAND - 1;
                selidx[(size_t)b * KSEL + r] = idx;
            }
        }
        if (tid == 0) selV[b] = V;
        return;
    }

    // ========================= DECODE =========================
    unsigned long long* pm = reinterpret_cast<unsigned long long*>(smem);
    const int half = tid >> 9;          // 0: ch0-4 + cls 0-39; 1: cls 40-79
    const int pr = tid & 511;
    float* g = geo + (size_t)b * 6 * NCANDP;

    if (role <= 5) {
        // -------- float4 quad path (s52 roles 1-4, s26 role 5) --------
        const float* in; const float* anch; int HW, Hdim, pb, nb, g0, nG; float ts;
        if (role <= 4) { in = in52; anch = a52; HW = 2704; Hdim = 52; ts = 8.f;
                         pb = PB52; nb = NC13 + NC26; g0 = (role - 1) * 512; nG = 2028; }
        else           { in = in26; anch = a26; HW = 676;  Hdim = 26; ts = 16.f;
                         pb = PB26; nb = NC13; g0 = 0; nG = 507; }
        const int gq = g0 + pr;
        const bool act = (gq < nG);
        const int gpa = HW >> 2;
        int a = 0, g4 = 0, hw = 0;
        const float4* p4 = nullptr;
        if (act) {
            a = gq / gpa; g4 = gq - a * gpa; hw = g4 * 4;
            p4 = reinterpret_cast<const float4*>(
                in + ((size_t)b * 255 + (size_t)a * 85) * HW) + g4;
        }

        unsigned long long m0 = 0, m1 = 0, m2 = 0, m3 = 0;
        if (act) {
            const int crow = (half == 0) ? 5 : 45;     // class rows base
            const int cb0  = (half == 0) ? 0 : 40;     // class index base
            const float4* pc = p4 + (size_t)crow * gpa;
            for (int cb = 0; cb < 10; ++cb) {
                float4 v[4];
                #pragma unroll
                for (int j = 0; j < 4; ++j) v[j] = pc[(size_t)(cb * 4 + j) * gpa];
                #pragma unroll
                for (int j = 0; j < 4; ++j) {
                    const int c = cb0 + cb * 4 + j;
                    unsigned long long k;
                    k = cls_key(v[j].x, c); if (k > m0) m0 = k;
                    k = cls_key(v[j].y, c); if (k > m1) m1 = k;
                    k = cls_key(v[j].z, c); if (k > m2) m2 = k;
                    k = cls_key(v[j].w, c); if (k > m3) m3 = k;
                }
            }
        }
        if (half == 1 && act) {
            pm[pr * 4 + 0] = m0; pm[pr * 4 + 1] = m1;
            pm[pr * 4 + 2] = m2; pm[pr * 4 + 3] = m3;
        }
        __syncthreads();
        if (half == 0 && act) {
            if (pm[pr * 4 + 0] > m0) m0 = pm[pr * 4 + 0];
            if (pm[pr * 4 + 1] > m1) m1 = pm[pr * 4 + 1];
            if (pm[pr * 4 + 2] > m2) m2 = pm[pr * 4 + 2];
            if (pm[pr * 4 + 3] > m3) m3 = pm[pr * 4 + 3];
            const int c0 = 127 - (int)(m0 & 0x7Full);
            const int c1 = 127 - (int)(m1 & 0x7Full);
            const int c2 = 127 - (int)(m2 & 0x7Full);
            const int c3 = 127 - (int)(m3 & 0x7Full);
            const float4 txv = p4[0];
            const float4 tyv = p4[(size_t)gpa];
            const float4 twv = p4[(size_t)2 * gpa];
            const float4 thv = p4[(size_t)3 * gpa];
            const float4 xov = p4[(size_t)4 * gpa];
            const float aw = anch[2 * a], ah = anch[2 * a + 1];
            float4 X1v, Y1v, X2v, Y2v, CFv, CLv;
#define DECC(comp, j, cc) { \
            const int hwj = hw + j; \
            const int hj = hwj / Hdim, wj = hwj - hj * Hdim; \
            const float sx = 1.0f / (1.0f + expf(-txv.comp)); \
            const float sy = 1.0f / (1.0f + expf(-tyv.comp)); \
            const float cf = 1.0f / (1.0f + expf(-xov.comp)); \
            const float cx = ((float)wj + sx) * ts; \
            const float cy = ((float)hj + sy) * ts; \
            const float bw = aw * expf(twv.comp); \
            const float bh = ah * expf(thv.comp); \
            X1v.comp = cx - bw * 0.5f; Y1v.comp = cy - bh * 0.5f; \
            X2v.comp = cx + bw * 0.5f; Y2v.comp = cy + bh * 0.5f; \
            CFv.comp = cf; CLv.comp = (float)cc; }
            DECC(x, 0, c0) DECC(y, 1, c1) DECC(z, 2, c2) DECC(w, 3, c3)
#undef DECC
            const int i0 = pb + a * HW + hw;
            *reinterpret_cast<float4*>(g + (size_t)0 * NCANDP + i0) = X1v;
            *reinterpret_cast<float4*>(g + (size_t)1 * NCANDP + i0) = Y1v;
            *reinterpret_cast<float4*>(g + (size_t)2 * NCANDP + i0) = X2v;
            *reinterpret_cast<float4*>(g + (size_t)3 * NCANDP + i0) = Y2v;
            *reinterpret_cast<float4*>(g + (size_t)4 * NCANDP + i0) = CFv;
            *reinterpret_cast<float4*>(g + (size_t)5 * NCANDP + i0) = CLv;
        }
        return;
    }

    // -------- scalar path (s13, role 6) --------
    {
        const bool act = (pr < NC13);
        int a = 0, hw = 0;
        const float* p = nullptr;
        if (act) {
            a = pr / 169; hw = pr - a * 169;
            p = in13 + ((size_t)b * 255 + (size_t)a * 85) * 169 + hw;
        }
        unsigned long long m = 0;
        if (act) {
            const int crow = (half == 0) ? 5 : 45;
            const int cb0  = (half == 0) ? 0 : 40;
            const float* pc = p + (size_t)crow * 169;
            for (int cb = 0; cb < 10; ++cb) {
                float v[4];
                #pragma unroll
                for (int j = 0; j < 4; ++j) v[j] = pc[(size_t)(cb * 4 + j) * 169];
                #pragma unroll
                for (int j = 0; j < 4; ++j) {
                    const unsigned long long k = cls_key(v[j], cb0 + cb * 4 + j);
                    if (k > m) m = k;
                }
            }
        }
        if (half == 1 && act) pm[pr] = m;
        __syncthreads();
        if (half == 0 && act) {
            if (pm[pr] > m) m = pm[pr];
            const int cls = 127 - (int)(m & 0x7Full);
            const float tx = p[0];
            const float ty = p[169];
            const float tw = p[2 * 169];
            const float th = p[3 * 169];
            const float xo = p[4 * 169];
            const int h = hw / 13, w = hw - h * 13;
            const float sx = 1.0f / (1.0f + expf(-tx));
            const float sy = 1.0f / (1.0f + expf(-ty));
            const float cf = 1.0f / (1.0f + expf(-xo));
            const float cx = ((float)w + sx) * 32.f;
            const float cy = ((float)h + sy) * 32.f;
            const float bw = a13[2 * a] * expf(tw);
            const float bh = a13[2 * a + 1] * expf(th);
            const int i = a * 169 + hw;    // PB13 == 0
            g[(size_t)0 * NCANDP + i] = cx - bw * 0.5f;
            g[(size_t)1 * NCANDP + i] = cy - bh * 0.5f;
            g[(size_t)2 * NCANDP + i] = cx + bw * 0.5f;
            g[(size_t)3 * NCANDP + i] = cy + bh * 0.5f;
            g[(size_t)4 * NCANDP + i] = cf;
            g[(size_t)5 * NCANDP + i] = (float)cls;
        }
    }
}

// ---------------------------------------------------------------------------
// NMS kernel (verified body). One block per image, 512 threads.
// ---------------------------------------------------------------------------
__global__ __launch_bounds__(512) void nms_kernel(
    const float* __restrict__ geo,
    const int* __restrict__ selidx,
    const int* __restrict__ selV,
    float* __restrict__ out)
{
    __shared__ float X1[KSEL], Y1[KSEL], X2[KSEL], Y2[KSEL], AR[KSEL];
    __shared__ unsigned int CM[80 * CMW];
    __shared__ unsigned int SUP[KSEL * SUPW];
    __shared__ unsigned int KEEP[16];

    const int b = blockIdx.x;
    const int tid = threadIdx.x;

    const int n = selidx[(size_t)b * KSEL + tid];
    int pb, HW, nb;
    if (n < NC13)             { pb = PB13; HW = 169;  nb = 0; }
    else if (n < NC13 + NC26) { pb = PB26; HW = 676;  nb = NC13; }
    else                      { pb = PB52; HW = 2704; nb = NC13 + NC26; }
    const int loc = n - nb;
    const int hw = loc / 3, a = loc - 3 * hw;
    const int i = pb + a * HW + hw;

    const float* g = geo + (size_t)b * 6 * NCANDP;
    const float x1 = g[(size_t)0 * NCANDP + i];
    const float y1 = g[(size_t)1 * NCANDP + i];
    const float x2 = g[(size_t)2 * NCANDP + i];
    const float y2 = g[(size_t)3 * NCANDP + i];
    const float cf = g[(size_t)4 * NCANDP + i];
    const int ci = (int)g[(size_t)5 * NCANDP + i];
    const float ar = (x2 - x1) * (y2 - y1);
    X1[tid] = x1; Y1[tid] = y1; X2[tid] = x2; Y2[tid] = y2; AR[tid] = ar;
    for (int q = tid; q < 80 * CMW; q += KSEL) CM[q] = 0;
    const int V0 = selV[b];
    const int V = (V0 < KSEL) ? V0 : KSEL;      // valid is a prefix of ranks
    __syncthreads();

    atomicOr(&CM[ci * CMW + (tid >> 5)], 1u << (tid & 31));
    __syncthreads();

    for (int wj = 0; wj < 16; ++wj) {
        unsigned int m = CM[ci * CMW + wj];
        unsigned int bits = 0;
        while (m) {
            const int bit = __ffs(m) - 1;
            m &= m - 1;
            const int j = wj * 32 + bit;
            const float iw = fminf(x2, X2[j]) - fmaxf(x1, X1[j]);
            const float ih = fminf(y2, Y2[j]) - fmaxf(y1, Y1[j]);
            if (iw > 0.0f && ih > 0.0f) {
                const float inter = iw * ih;
                if (inter > 0.3f * (ar + AR[j] - inter + 1e-9f))
                    bits |= (1u << bit);
            }
        }
        SUP[tid * SUPW + wj] = bits;
    }
    __syncthreads();

    // sequential greedy scan (exact lax.scan semantics), wave 0 only
    if (tid < 64) {
        unsigned int keepw = 0;       // lanes 0..15 hold the 512-bit keep mask
        unsigned int buf[16];
        #pragma unroll
        for (int q = 0; q < 16; ++q)
            buf[q] = (tid < 16) ? SUP[q * SUPW + tid] : 0u;
        for (int gg = 0; gg < 32; ++gg) {
            unsigned int nbuf[16] = {0};
            if (gg < 31) {
                #pragma unroll
                for (int q = 0; q < 16; ++q)
                    nbuf[q] = (tid < 16) ? SUP[((gg + 1) * 16 + q) * SUPW + tid] : 0u;
            }
            #pragma unroll
            for (int q = 0; q < 16; ++q) {
                const int ii = gg * 16 + q;
                const bool anysup = __any((keepw & buf[q]) != 0u);
                const bool ki = (ii < V) && !anysup;
                if (ki && tid == (ii >> 5)) keepw |= (1u << (ii & 31));
            }
            #pragma unroll
            for (int q = 0; q < 16; ++q) buf[q] = nbuf[q];
        }
        if (tid < 16) KEEP[tid] = keepw;
    }
    __syncthreads();

    const float kf = ((KEEP[tid >> 5] >> (tid & 31)) & 1u) ? 1.0f : 0.0f;
    float* dst = out + ((size_t)b * KSEL + tid) * 7;
    dst[0] = x1; dst[1] = y1; dst[2] = x2; dst[3] = y2;
    dst[4] = cf; dst[5] = (float)ci; dst[6] = kf;
}

// ---------------------------------------------------------------------------
extern "C" void kernel_launch(void* const* d_in, const int* in_sizes, int n_in,
                              void* d_out, int out_size, void* d_ws, size_t ws_size,
                              hipStream_t stream)
{
    (void)n_in; (void)out_size; (void)ws_size;
    const float* in13 = (const float*)d_in[0];
    const float* in26 = (const float*)d_in[1];
    const float* in52 = (const float*)d_in[2];
    const float* a13  = (const float*)d_in[3];
    const float* a26  = (const float*)d_in[4];
    const float* a52  = (const float*)d_in[5];
    float* out = (float*)d_out;
    const int B = in_sizes[0] / (255 * 169);

    char* w = (char*)d_ws;
    float* geo = (float*)w;
    w += ((size_t)B * 6 * NCANDP * sizeof(float) + 255) & ~(size_t)255;
    int* selidx = (int*)w;  w += ((size_t)B * KSEL * sizeof(int) + 255) & ~(size_t)255;
    int* selV   = (int*)w;  w += ((size_t)B * sizeof(int) + 255) & ~(size_t)255;

    mega_kernel<<<dim3(B * 7), 1024, 0, stream>>>(
        in13, in26, in52, a13, a26, a52, geo, selidx, selV);
    nms_kernel<<<dim3(B), 512, 0, stream>>>(geo, selidx, selV, out);
}